// Round 8
// baseline (103.996 us; speedup 1.0000x reference)
//
#include <hip/hip_runtime.h>
#include <hip/hip_fp16.h>

// SDDMM: out[n] = mask_vals[n] + dot(mat1[rows[n], :], mat2[:, cols[n]])
// NNZ = 1e6, M = N = 8192, K = 128, fp32 in/out. Indices int32 per harness.
//
// History:
// R1: fp32 working set 8 MB > 4 MiB/XCD L2 -> 277 MB fabric traffic, 80 us.
// R2: fp16 (4 MB, L2-resident per XCD) -> 63 us, latency-bound (MLP=2).
// R3: batch 4 nnz per 16-lane group (MLP=8) -> sddmm ~42 us. Random-gather
//     service measured at ~6.45 cyc/line/CU (~12 TB/s effective).
// R4/R5: col-slab sort + LDS slab: sort machinery costs 25-30 us > 15-20 us
//     saved. Regressed twice; abandoned.
// R6: R3 + single fused prep kernel -> 100.1 us total (best).
// R7: NT hints on streaming traffic (rows/cols/mask/out, prep inputs) so the
//     16 MB of streams stop evicting the 4 MB fp16 gather set from each XCD
//     L2. R7a failed to compile: __builtin_nontemporal_* rejects
//     HIP_vector_type; must use native clang ext_vector_type pointers.

#define KDIM 128

typedef _Float16 half2v __attribute__((ext_vector_type(2)));
typedef float fx4 __attribute__((ext_vector_type(4)));
typedef int ix4 __attribute__((ext_vector_type(4)));

union F4H8 {
  fx4 f4;
  half2v h2[4];
  _Float16 h[8];
};

// ---------- K1: convert mat1 -> fp16, transpose+convert mat2 -> fp16 ----------

__global__ __launch_bounds__(256) void prep_kernel(
    const float* __restrict__ mat1, _Float16* __restrict__ m1h, int m1_sz,
    const float* __restrict__ mat2, _Float16* __restrict__ m2th, int N,
    int nconvblk) {
  __shared__ float tile[32][33];
  int blk = blockIdx.x;
  if (blk < nconvblk) {
    // mat1 [M,128] fp32 -> m1h fp16, same layout. 8 elems/thread.
    int i = (blk * 256 + threadIdx.x) * 8;
    if (i < m1_sz) {
      const fx4* p = (const fx4*)(mat1 + i);
      fx4 x0 = __builtin_nontemporal_load(p);      // streamed once
      fx4 x1 = __builtin_nontemporal_load(p + 1);
      F4H8 o;
      o.h[0] = (_Float16)x0.x; o.h[1] = (_Float16)x0.y;
      o.h[2] = (_Float16)x0.z; o.h[3] = (_Float16)x0.w;
      o.h[4] = (_Float16)x1.x; o.h[5] = (_Float16)x1.y;
      o.h[6] = (_Float16)x1.z; o.h[7] = (_Float16)x1.w;
      *(fx4*)(m1h + i) = o.f4;  // reuse set: keep cached
    }
    return;
  }
  // mat2 [128, N] fp32 -> m2th [N, 128] fp16. 32x32 tiles via padded LDS.
  int u = blk - nconvblk;
  int nbx = N / 32;
  int bx = (u % nbx) * 32;  // N dim
  int by = (u / nbx) * 32;  // K dim
  int tx = threadIdx.x & 31;
  int ty = threadIdx.x >> 5;  // 0..7
#pragma unroll
  for (int j = 0; j < 32; j += 8) {
    tile[ty + j][tx] =
        __builtin_nontemporal_load(&mat2[(size_t)(by + ty + j) * N + (bx + tx)]);
  }
  __syncthreads();
#pragma unroll
  for (int j = 0; j < 32; j += 8) {
    m2th[(size_t)(bx + ty + j) * KDIM + (by + tx)] = (_Float16)tile[tx][ty + j];
  }
}

// ---------- K2: sddmm, 16-lane group x 4 nnz (MLP=8) ----------

__device__ __forceinline__ float dot8(const F4H8& a, const F4H8& b) {
  float s = 0.f;
#if __has_builtin(__builtin_amdgcn_fdot2)
#pragma unroll
  for (int j = 0; j < 4; ++j) s = __builtin_amdgcn_fdot2(a.h2[j], b.h2[j], s, false);
#else
#pragma unroll
  for (int j = 0; j < 8; ++j) s += (float)a.h[j] * (float)b.h[j];
#endif
  return s;
}

__device__ __forceinline__ float red16(float s) {
  s += __shfl_xor(s, 8);
  s += __shfl_xor(s, 4);
  s += __shfl_xor(s, 2);
  s += __shfl_xor(s, 1);
  return s;
}

__global__ __launch_bounds__(256) void sddmm_f16_b4_kernel(
    const float* __restrict__ mask_vals, const int* __restrict__ rows,
    const int* __restrict__ cols, const _Float16* __restrict__ m1,
    const _Float16* __restrict__ m2t, float* __restrict__ out, int nnz) {
  int tid = blockIdx.x * 256 + threadIdx.x;
  int grp = tid >> 4;   // 16 lanes per group; group handles 4 nnz
  int lane = tid & 15;
  int g0 = grp * 4;
  if (g0 >= nnz) return;
  if (g0 + 4 <= nnz) {
    // Group-uniform broadcast index loads; NT: streamed once, don't cache.
    ix4 r4 = __builtin_nontemporal_load((const ix4*)(rows + g0));
    ix4 c4 = __builtin_nontemporal_load((const ix4*)(cols + g0));

    // 8 independent 16B gathers in flight before any arithmetic.
    // These hit the fp16 reuse set -> normal caching.
    F4H8 a0, a1, a2, a3, b0, b1, b2, b3;
    a0.f4 = ((const fx4*)(m1 + (size_t)r4.x * KDIM))[lane];
    a1.f4 = ((const fx4*)(m1 + (size_t)r4.y * KDIM))[lane];
    a2.f4 = ((const fx4*)(m1 + (size_t)r4.z * KDIM))[lane];
    a3.f4 = ((const fx4*)(m1 + (size_t)r4.w * KDIM))[lane];
    b0.f4 = ((const fx4*)(m2t + (size_t)c4.x * KDIM))[lane];
    b1.f4 = ((const fx4*)(m2t + (size_t)c4.y * KDIM))[lane];
    b2.f4 = ((const fx4*)(m2t + (size_t)c4.z * KDIM))[lane];
    b3.f4 = ((const fx4*)(m2t + (size_t)c4.w * KDIM))[lane];

    float s0 = red16(dot8(a0, b0));
    float s1 = red16(dot8(a1, b1));
    float s2 = red16(dot8(a2, b2));
    float s3 = red16(dot8(a3, b3));

    if (lane == 0) {
      fx4 mv = __builtin_nontemporal_load((const fx4*)(mask_vals + g0));
      fx4 o;
      o.x = mv.x + s0;
      o.y = mv.y + s1;
      o.z = mv.z + s2;
      o.w = mv.w + s3;
      // lanes 0/16/32/48 -> contiguous 64 B; NT store: never re-read.
      __builtin_nontemporal_store(o, (fx4*)(out + g0));
    }
  } else {
    for (int g = g0; g < nnz; ++g) {
      F4H8 a, b;
      a.f4 = ((const fx4*)(m1 + (size_t)rows[g] * KDIM))[lane];
      b.f4 = ((const fx4*)(m2t + (size_t)cols[g] * KDIM))[lane];
      float sv = red16(dot8(a, b));
      if (lane == 0) out[g] = mask_vals[g] + sv;
    }
  }
}

// ---------- fallback: fp32 strided, no workspace needed ----------

__global__ __launch_bounds__(256) void sddmm16_strided_kernel(
    const float* __restrict__ mask_vals, const int* __restrict__ rows,
    const int* __restrict__ cols, const float* __restrict__ mat1,
    const float* __restrict__ mat2, float* __restrict__ out, int nnz, int N) {
  int tid = blockIdx.x * 256 + threadIdx.x;
  int g = tid >> 4;
  int lane = tid & 15;
  if (g >= nnz) return;
  int r = rows[g];
  int c = cols[g];
  const float* arow = mat1 + (size_t)r * KDIM;
  float s = 0.f;
#pragma unroll
  for (int j = 0; j < 8; ++j) {
    int k = lane + 16 * j;
    s += arow[k] * mat2[(size_t)k * N + c];
  }
  s = red16(s);
  if (lane == 0) out[g] = mask_vals[g] + s;
}

// ---------- launch ----------

extern "C" void kernel_launch(void* const* d_in, const int* in_sizes, int n_in,
                              void* d_out, int out_size, void* d_ws, size_t ws_size,
                              hipStream_t stream) {
  const float* mask_vals = (const float*)d_in[0];
  const int*   rows      = (const int*)d_in[1];
  const int*   cols      = (const int*)d_in[2];
  const float* mat1      = (const float*)d_in[3];
  const float* mat2      = (const float*)d_in[4];
  float*       out       = (float*)d_out;

  int nnz   = in_sizes[0];
  int m1_sz = in_sizes[3];        // M * 128
  int N     = in_sizes[4] / KDIM; // mat2 is [128, N]

  auto align256 = [](size_t x) { return (x + 255) & ~(size_t)255; };
  size_t need = align256((size_t)m1_sz * 2) + align256((size_t)KDIM * N * 2);

  if (ws_size >= need && (m1_sz % 2048) == 0 && (N % 32) == 0) {
    _Float16* m1h  = (_Float16*)d_ws;
    _Float16* m2th = (_Float16*)((char*)d_ws + align256((size_t)m1_sz * 2));

    int nconvblk  = (m1_sz / 8 + 255) / 256;
    int ntransblk = (N / 32) * (KDIM / 32);
    prep_kernel<<<nconvblk + ntransblk, 256, 0, stream>>>(
        mat1, m1h, m1_sz, mat2, m2th, N, nconvblk);

    int groups = (nnz + 3) / 4;
    int blocks = (groups * 16 + 255) / 256;
    sddmm_f16_b4_kernel<<<blocks, 256, 0, stream>>>(mask_vals, rows, cols,
                                                    m1h, m2th, out, nnz);
  } else {
    int blocks = (int)(((size_t)nnz * 16 + 255) / 256);
    sddmm16_strided_kernel<<<blocks, 256, 0, stream>>>(mask_vals, rows, cols,
                                                       mat1, mat2, out, nnz, N);
  }
}

// Round 9
// 100.478 us; speedup vs baseline: 1.0350x; 1.0350x over previous
//
#include <hip/hip_runtime.h>
#include <hip/hip_fp16.h>

// SDDMM: out[n] = mask_vals[n] + dot(mat1[rows[n], :], mat2[:, cols[n]])
// NNZ = 1e6, M = N = 8192, K = 128, fp32 in/out. Indices int32 per harness.
//
// Final structure (best measured: 100.1 us total, R6):
//   K1 prep: mat1 fp32->fp16 copy + mat2 [128,N] -> [N,128] fp16 transpose
//            (both gather operands become contiguous 256 B rows, 4 MB total
//            -> L2-resident per XCD).
//   K2 sddmm: 16-lane group x 4 nnz, 8 independent 16 B gathers in flight,
//            fdot2 + 4-step shfl reduce, coalesced 64 B out stores.
//
// Ladder: R1 fp32 naive-tiled 80 us (L2-miss fabric traffic 277 MB) ->
// R2 fp16 L2-resident 63 us (latency-bound, MLP=2) -> R3 batch-4 MLP=8,
// sddmm ~42 us -> R6 fused prep, 100.1 us total. Measured walls:
// - random-gather service ~6.4 cyc/line/CU (~12 TB/s effective); MLP
//   saturated, so more outstanding loads don't help.
// - fp8 rejected (absmax ~4 > 1.27 threshold); fp16 absmax 0.25 passes.
// - col-slab sort + LDS slab (R4/R5): sort costs 25-30 us > 15-20 saved.
// - NT cache hints on streams (R8): neutral-to-negative (104.0 us).
// Remaining total is ~50-55 us fixed harness window (256 MiB ws-poison
// fill ~46 us + input restores) + ~3 us prep + ~42 us sddmm at the
// random-gather wall.

#define KDIM 128

typedef _Float16 half2v __attribute__((ext_vector_type(2)));

union F4H8 {
  float4 f4;
  half2v h2[4];
  _Float16 h[8];
};

// ---------- K1: convert mat1 -> fp16, transpose+convert mat2 -> fp16 ----------

__global__ __launch_bounds__(256) void prep_kernel(
    const float* __restrict__ mat1, _Float16* __restrict__ m1h, int m1_sz,
    const float* __restrict__ mat2, _Float16* __restrict__ m2th, int N,
    int nconvblk) {
  __shared__ float tile[32][33];
  int blk = blockIdx.x;
  if (blk < nconvblk) {
    // mat1 [M,128] fp32 -> m1h fp16, same layout. 8 elems/thread.
    int i = (blk * 256 + threadIdx.x) * 8;
    if (i < m1_sz) {
      const float4* p = (const float4*)(mat1 + i);
      float4 x0 = p[0];
      float4 x1 = p[1];
      F4H8 o;
      o.h[0] = (_Float16)x0.x; o.h[1] = (_Float16)x0.y;
      o.h[2] = (_Float16)x0.z; o.h[3] = (_Float16)x0.w;
      o.h[4] = (_Float16)x1.x; o.h[5] = (_Float16)x1.y;
      o.h[6] = (_Float16)x1.z; o.h[7] = (_Float16)x1.w;
      *(float4*)(m1h + i) = o.f4;
    }
    return;
  }
  // mat2 [128, N] fp32 -> m2th [N, 128] fp16. 32x32 tiles via padded LDS.
  int u = blk - nconvblk;
  int nbx = N / 32;
  int bx = (u % nbx) * 32;  // N dim
  int by = (u / nbx) * 32;  // K dim
  int tx = threadIdx.x & 31;
  int ty = threadIdx.x >> 5;  // 0..7
#pragma unroll
  for (int j = 0; j < 32; j += 8) {
    tile[ty + j][tx] = mat2[(size_t)(by + ty + j) * N + (bx + tx)];
  }
  __syncthreads();
#pragma unroll
  for (int j = 0; j < 32; j += 8) {
    m2th[(size_t)(bx + ty + j) * KDIM + (by + tx)] = (_Float16)tile[tx][ty + j];
  }
}

// ---------- K2: sddmm, 16-lane group x 4 nnz (MLP=8) ----------

__device__ __forceinline__ float dot8(const F4H8& a, const F4H8& b) {
  float s = 0.f;
#if __has_builtin(__builtin_amdgcn_fdot2)
#pragma unroll
  for (int j = 0; j < 4; ++j) s = __builtin_amdgcn_fdot2(a.h2[j], b.h2[j], s, false);
#else
#pragma unroll
  for (int j = 0; j < 8; ++j) s += (float)a.h[j] * (float)b.h[j];
#endif
  return s;
}

__device__ __forceinline__ float red16(float s) {
  s += __shfl_xor(s, 8);
  s += __shfl_xor(s, 4);
  s += __shfl_xor(s, 2);
  s += __shfl_xor(s, 1);
  return s;
}

__global__ __launch_bounds__(256) void sddmm_f16_b4_kernel(
    const float* __restrict__ mask_vals, const int* __restrict__ rows,
    const int* __restrict__ cols, const _Float16* __restrict__ m1,
    const _Float16* __restrict__ m2t, float* __restrict__ out, int nnz) {
  int tid = blockIdx.x * 256 + threadIdx.x;
  int grp = tid >> 4;   // 16 lanes per group; group handles 4 nnz
  int lane = tid & 15;
  int g0 = grp * 4;
  if (g0 >= nnz) return;
  if (g0 + 4 <= nnz) {
    // Group-uniform broadcast index loads.
    int4 r4 = *(const int4*)(rows + g0);
    int4 c4 = *(const int4*)(cols + g0);

    // 8 independent 16B gathers in flight before any arithmetic.
    F4H8 a0, a1, a2, a3, b0, b1, b2, b3;
    a0.f4 = ((const float4*)(m1 + (size_t)r4.x * KDIM))[lane];
    a1.f4 = ((const float4*)(m1 + (size_t)r4.y * KDIM))[lane];
    a2.f4 = ((const float4*)(m1 + (size_t)r4.z * KDIM))[lane];
    a3.f4 = ((const float4*)(m1 + (size_t)r4.w * KDIM))[lane];
    b0.f4 = ((const float4*)(m2t + (size_t)c4.x * KDIM))[lane];
    b1.f4 = ((const float4*)(m2t + (size_t)c4.y * KDIM))[lane];
    b2.f4 = ((const float4*)(m2t + (size_t)c4.z * KDIM))[lane];
    b3.f4 = ((const float4*)(m2t + (size_t)c4.w * KDIM))[lane];

    float s0 = red16(dot8(a0, b0));
    float s1 = red16(dot8(a1, b1));
    float s2 = red16(dot8(a2, b2));
    float s3 = red16(dot8(a3, b3));

    if (lane == 0) {
      float4 mv = *(const float4*)(mask_vals + g0);
      float4 o = {mv.x + s0, mv.y + s1, mv.z + s2, mv.w + s3};
      *(float4*)(out + g0) = o;  // lanes 0/16/32/48 -> contiguous 64 B
    }
  } else {
    for (int g = g0; g < nnz; ++g) {
      F4H8 a, b;
      a.f4 = ((const float4*)(m1 + (size_t)rows[g] * KDIM))[lane];
      b.f4 = ((const float4*)(m2t + (size_t)cols[g] * KDIM))[lane];
      float sv = red16(dot8(a, b));
      if (lane == 0) out[g] = mask_vals[g] + sv;
    }
  }
}

// ---------- fallback: fp32 strided, no workspace needed ----------

__global__ __launch_bounds__(256) void sddmm16_strided_kernel(
    const float* __restrict__ mask_vals, const int* __restrict__ rows,
    const int* __restrict__ cols, const float* __restrict__ mat1,
    const float* __restrict__ mat2, float* __restrict__ out, int nnz, int N) {
  int tid = blockIdx.x * 256 + threadIdx.x;
  int g = tid >> 4;
  int lane = tid & 15;
  if (g >= nnz) return;
  int r = rows[g];
  int c = cols[g];
  const float* arow = mat1 + (size_t)r * KDIM;
  float s = 0.f;
#pragma unroll
  for (int j = 0; j < 8; ++j) {
    int k = lane + 16 * j;
    s += arow[k] * mat2[(size_t)k * N + c];
  }
  s = red16(s);
  if (lane == 0) out[g] = mask_vals[g] + s;
}

// ---------- launch ----------

extern "C" void kernel_launch(void* const* d_in, const int* in_sizes, int n_in,
                              void* d_out, int out_size, void* d_ws, size_t ws_size,
                              hipStream_t stream) {
  const float* mask_vals = (const float*)d_in[0];
  const int*   rows      = (const int*)d_in[1];
  const int*   cols      = (const int*)d_in[2];
  const float* mat1      = (const float*)d_in[3];
  const float* mat2      = (const float*)d_in[4];
  float*       out       = (float*)d_out;

  int nnz   = in_sizes[0];
  int m1_sz = in_sizes[3];        // M * 128
  int N     = in_sizes[4] / KDIM; // mat2 is [128, N]

  auto align256 = [](size_t x) { return (x + 255) & ~(size_t)255; };
  size_t need = align256((size_t)m1_sz * 2) + align256((size_t)KDIM * N * 2);

  if (ws_size >= need && (m1_sz % 2048) == 0 && (N % 32) == 0) {
    _Float16* m1h  = (_Float16*)d_ws;
    _Float16* m2th = (_Float16*)((char*)d_ws + align256((size_t)m1_sz * 2));

    int nconvblk  = (m1_sz / 8 + 255) / 256;
    int ntransblk = (N / 32) * (KDIM / 32);
    prep_kernel<<<nconvblk + ntransblk, 256, 0, stream>>>(
        mat1, m1h, m1_sz, mat2, m2th, N, nconvblk);

    int groups = (nnz + 3) / 4;
    int blocks = (groups * 16 + 255) / 256;
    sddmm_f16_b4_kernel<<<blocks, 256, 0, stream>>>(mask_vals, rows, cols,
                                                    m1h, m2th, out, nnz);
  } else {
    int blocks = (int)(((size_t)nnz * 16 + 255) / 256);
    sddmm16_strided_kernel<<<blocks, 256, 0, stream>>>(mask_vals, rows, cols,
                                                       mat1, mat2, out, nnz, N);
  }
}